// Round 1
// baseline (21943.018 us; speedup 1.0000x reference)
//
#include <hip/hip_runtime.h>

#define BB 16
#define NN 4096
#define CC 64
#define SS 1024
#define KK 32
#define NPT 1024
#define NS 32
#define NROWS (BB*SS*KK)   // 524288

// ============================= FPS =============================
// one block per batch; 256 threads x 16 points in registers.
__global__ __launch_bounds__(256) void fps_kernel(const float* __restrict__ xyz,
                                                  float* __restrict__ newxyz)
{
#pragma clang fp contract(off)
  const int b = blockIdx.x;
  const int t = threadIdx.x;
  const float* xb = xyz + (size_t)b * NN * 3;
  float px[16], py[16], pz[16], dist[16];
#pragma unroll
  for (int j = 0; j < 16; ++j) {
    const float* p = xb + (size_t)(t + j*256) * 3;
    px[j] = p[0]; py[j] = p[1]; pz[j] = p[2];
    dist[j] = 1e10f;
  }
  __shared__ float cx, cy, cz;
  __shared__ float wv[4];
  __shared__ int   wi[4];
  float* outb = newxyz + (size_t)b * NPT * 3;
  if (t == 0) {
    cx = px[0]; cy = py[0]; cz = pz[0];
    outb[0] = px[0]; outb[1] = py[0]; outb[2] = pz[0];
  }
  __syncthreads();
  for (int s = 0; s < NPT; ++s) {
    const float ccx = cx, ccy = cy, ccz = cz;
    float best = -1.0f; int bi = 0;
#pragma unroll
    for (int j = 0; j < 16; ++j) {
      float dx = px[j] - ccx;
      float dy = py[j] - ccy;
      float dz = pz[j] - ccz;
      float d = dx*dx;
      d = d + dy*dy;
      d = d + dz*dz;
      float dn = fminf(dist[j], d);
      dist[j] = dn;
      bool gt = dn > best;           // strict > keeps lowest index on ties (argmax-first)
      best = gt ? dn : best;
      bi   = gt ? (t + j*256) : bi;
    }
#pragma unroll
    for (int off = 32; off > 0; off >>= 1) {
      float ov = __shfl_down(best, off);
      int   oi = __shfl_down(bi, off);
      if (ov > best || (ov == best && oi < bi)) { best = ov; bi = oi; }
    }
    if ((t & 63) == 0) { wv[t >> 6] = best; wi[t >> 6] = bi; }
    __syncthreads();
    float fb = wv[0]; int fi = wi[0];
#pragma unroll
    for (int w = 1; w < 4; ++w) {
      float v = wv[w]; int i2 = wi[w];
      if (v > fb || (v == fb && i2 < fi)) { fb = v; fi = i2; }
    }
    if (s + 1 < NPT && t == (fi & 255)) {
      int jj = fi >> 8;
      float sx = 0.f, sy = 0.f, sz = 0.f;
#pragma unroll
      for (int j = 0; j < 16; ++j) if (jj == j) { sx = px[j]; sy = py[j]; sz = pz[j]; } // static idx, no scratch
      cx = sx; cy = sy; cz = sz;
      outb[(size_t)(s+1)*3 + 0] = sx;
      outb[(size_t)(s+1)*3 + 1] = sy;
      outb[(size_t)(s+1)*3 + 2] = sz;
    }
    __syncthreads();
  }
}

// ============================ Ball query ============================
// thread per centroid; 32-deep insertion list in LDS (stride 33 -> bank spread).
// Distance/ordering replicates reference: d = sqrt(max(|c|^2+|x|^2-2c.x, 0)),
// stable ties -> lower index (insertion with strict >).
__global__ __launch_bounds__(128) void ballq_kernel(const float* __restrict__ xyz,
                                                    const float* __restrict__ newxyz,
                                                    int* __restrict__ idxout)
{
#pragma clang fp contract(off)
  const int t = threadIdx.x;
  const int sidx = blockIdx.x * 128 + t;
  const int b = sidx >> 10;            // S = 1024
  __shared__ float chx[256], chy[256], chz[256];
  __shared__ float ld[128*33];
  __shared__ int   li[128*33];
  float* myd = &ld[t*33];
  int*   myi = &li[t*33];
  const float cxv = newxyz[(size_t)sidx*3 + 0];
  const float cyv = newxyz[(size_t)sidx*3 + 1];
  const float czv = newxyz[(size_t)sidx*3 + 2];
  float sqc = cxv*cxv; sqc = sqc + cyv*cyv; sqc = sqc + czv*czv;
  const float* xb = xyz + (size_t)b * NN * 3;
  int cnt = 0;
  float dmax = 1e30f;
  for (int c0 = 0; c0 < NN; c0 += 256) {
    __syncthreads();
#pragma unroll
    for (int q = 0; q < 2; ++q) {
      int p = t + q*128;
      const float* src = xb + (size_t)(c0 + p) * 3;
      chx[p] = src[0]; chy[p] = src[1]; chz[p] = src[2];
    }
    __syncthreads();
    for (int u = 0; u < 256; ++u) {
      float x = chx[u], y = chy[u], z = chz[u];
      float sqx = x*x; sqx = sqx + y*y; sqx = sqx + z*z;
      float dot = x*cxv; dot = dot + y*cyv; dot = dot + z*czv;
      float d2 = (sqc + sqx) - 2.0f*dot;
      float dist = sqrtf(fmaxf(d2, 0.0f));
      if (cnt < NS || dist < dmax) {
        int j = (cnt < NS) ? cnt : (NS - 1);
        while (j > 0 && myd[j-1] > dist) { myd[j] = myd[j-1]; myi[j] = myi[j-1]; --j; }
        myd[j] = dist; myi[j] = c0 + u;
        if (cnt < NS) ++cnt;
        if (cnt == NS) dmax = myd[NS-1];
      }
    }
  }
  int i0 = myi[0];
  int* ob = idxout + (size_t)sidx * NS;
#pragma unroll
  for (int j = 0; j < NS; ++j) {
    ob[j] = (myd[j] > 0.2f) ? i0 : myi[j];   // replace out-of-ball with nearest
  }
}

// ============================ Layer 0 ============================
// fused gather + concat + conv(67->64). W staged in LDS, reordered:
// columns [feat(64) | xyz(3) | pad] so feat is float4-aligned.
__global__ __launch_bounds__(256) void layer0_kernel(
    const float* __restrict__ xyz, const float* __restrict__ feat,
    const float* __restrict__ newxyz, const int* __restrict__ idx,
    const float* __restrict__ W, const float* __restrict__ bias,
    float* __restrict__ Y)
{
  constexpr int CIN = 67, CH = 68, COUT = 64;
  __shared__ float Wl[COUT*CH];
  for (int u = threadIdx.x; u < COUT*CH; u += 256) {
    int o = u / CH, j = u % CH;
    float w = 0.f;
    if (j < 64)      w = W[o*CIN + 3 + j];     // feat cols
    else if (j < 67) w = W[o*CIN + (j - 64)];  // xyz cols
    Wl[u] = w;
  }
  __syncthreads();
  const int r  = blockIdx.x*256 + threadIdx.x;   // < NROWS exactly
  const int bs = r >> 5;
  const int b  = bs >> 10;
  const int i  = idx[r];
  const float* fp = feat   + ((size_t)b*NN + i) * 64;
  const float* xp = xyz    + ((size_t)b*NN + i) * 3;
  const float* cp = newxyz + (size_t)bs * 3;
  float acc[COUT];
#pragma unroll
  for (int o = 0; o < COUT; ++o) acc[o] = bias[o];
#pragma unroll
  for (int q = 0; q < 16; ++q) {
    float4 v = *reinterpret_cast<const float4*>(fp + q*4);
#pragma unroll
    for (int o = 0; o < COUT; ++o) {
      float4 w = *reinterpret_cast<const float4*>(&Wl[o*CH + q*4]);
      acc[o] += v.x*w.x + v.y*w.y + v.z*w.z + v.w*w.w;
    }
  }
  {
    float gx = xp[0]-cp[0], gy = xp[1]-cp[1], gz = xp[2]-cp[2];
#pragma unroll
    for (int o = 0; o < COUT; ++o) {
      float4 w = *reinterpret_cast<const float4*>(&Wl[o*CH + 64]);
      acc[o] += gx*w.x + gy*w.y + gz*w.z;
    }
  }
  float* yr = Y + (size_t)r * 64;
#pragma unroll
  for (int o = 0; o < COUT; o += 4)
    *reinterpret_cast<float4*>(yr + o) = make_float4(acc[o], acc[o+1], acc[o+2], acc[o+3]);
}

// ============================ Layer 1 ============================
// reads raw Y0, applies BN0+ReLU inline, conv(64->64), writes Y in place
// (rows are independent for a 1x1 conv).
__global__ __launch_bounds__(256) void layer1_kernel(
    float* __restrict__ Y,
    const float* __restrict__ W, const float* __restrict__ bias,
    const float* __restrict__ sc, const float* __restrict__ sh)
{
  constexpr int COUT = 64;
  __shared__ float Wl[COUT*64];
  for (int u = threadIdx.x; u < COUT*64; u += 256) Wl[u] = W[u];
  __syncthreads();
  const size_t r = (size_t)blockIdx.x*256 + threadIdx.x;
  float* yr = Y + r * 64;
  float acc[COUT];
#pragma unroll
  for (int o = 0; o < COUT; ++o) acc[o] = bias[o];
#pragma unroll
  for (int q = 0; q < 16; ++q) {
    float4 v = *reinterpret_cast<const float4*>(yr + q*4);
    float i0 = fmaxf(0.f, sc[q*4+0]*v.x + sh[q*4+0]);
    float i1 = fmaxf(0.f, sc[q*4+1]*v.y + sh[q*4+1]);
    float i2 = fmaxf(0.f, sc[q*4+2]*v.z + sh[q*4+2]);
    float i3 = fmaxf(0.f, sc[q*4+3]*v.w + sh[q*4+3]);
#pragma unroll
    for (int o = 0; o < COUT; ++o) {
      float4 w = *reinterpret_cast<const float4*>(&Wl[o*64 + q*4]);
      acc[o] += i0*w.x + i1*w.y + i2*w.z + i3*w.w;
    }
  }
#pragma unroll
  for (int o = 0; o < COUT; o += 4)
    *reinterpret_cast<float4*>(yr + o) = make_float4(acc[o], acc[o+1], acc[o+2], acc[o+3]);
}

// ============================ Layer 2 ============================
// reads raw Y1, applies BN1+ReLU inline, conv(64->128) split 2 threads/row
// (64 couts each). Epilogue: max+min over K=32 (32-lane shuffle groups) and
// per-block channel sums/sumsq partials (64-lane shuffle reduce).
__global__ __launch_bounds__(256) void layer2_kernel(
    const float* __restrict__ Y,
    const float* __restrict__ W, const float* __restrict__ bias,
    const float* __restrict__ sc, const float* __restrict__ sh,
    float* __restrict__ Ymax, float* __restrict__ Ymin,
    float* __restrict__ part)
{
  __shared__ float Wl[128*64];
  __shared__ float pS[4*64], pQ[4*64];
  for (int u = threadIdx.x; u < 128*64; u += 256) Wl[u] = W[u];
  __syncthreads();
  const int t  = threadIdx.x;
  const int h  = t >> 7;            // cout half (uniform per wave)
  const int rl = t & 127;
  const size_t r = (size_t)blockIdx.x * 128 + rl;
  const float* yr = Y + r * 64;
  const float* Wh = &Wl[h * 64 * 64];
  float acc[64];
#pragma unroll
  for (int o = 0; o < 64; ++o) acc[o] = bias[h*64 + o];
#pragma unroll
  for (int q = 0; q < 16; ++q) {
    float4 v = *reinterpret_cast<const float4*>(yr + q*4);
    float i0 = fmaxf(0.f, sc[q*4+0]*v.x + sh[q*4+0]);
    float i1 = fmaxf(0.f, sc[q*4+1]*v.y + sh[q*4+1]);
    float i2 = fmaxf(0.f, sc[q*4+2]*v.z + sh[q*4+2]);
    float i3 = fmaxf(0.f, sc[q*4+3]*v.w + sh[q*4+3]);
#pragma unroll
    for (int o = 0; o < 64; ++o) {
      float4 w = *reinterpret_cast<const float4*>(&Wh[o*64 + q*4]);
      acc[o] += i0*w.x + i1*w.y + i2*w.z + i3*w.w;
    }
  }
  const int lane = t & 63;
  const size_t bs = r >> 5;
#pragma unroll
  for (int o4 = 0; o4 < 64; o4 += 4) {
    float a0 = acc[o4+0], a1 = acc[o4+1], a2 = acc[o4+2], a3 = acc[o4+3];
    float b0 = a0, b1 = a1, b2 = a2, b3 = a3;
#pragma unroll
    for (int m = 16; m > 0; m >>= 1) {
      a0 = fmaxf(a0, __shfl_xor(a0, m));
      a1 = fmaxf(a1, __shfl_xor(a1, m));
      a2 = fmaxf(a2, __shfl_xor(a2, m));
      a3 = fmaxf(a3, __shfl_xor(a3, m));
      b0 = fminf(b0, __shfl_xor(b0, m));
      b1 = fminf(b1, __shfl_xor(b1, m));
      b2 = fminf(b2, __shfl_xor(b2, m));
      b3 = fminf(b3, __shfl_xor(b3, m));
    }
    if ((lane & 31) == 0) {
      *reinterpret_cast<float4*>(Ymax + bs*128 + h*64 + o4) = make_float4(a0,a1,a2,a3);
      *reinterpret_cast<float4*>(Ymin + bs*128 + h*64 + o4) = make_float4(b0,b1,b2,b3);
    }
  }
  const int wave = t >> 6;
#pragma unroll
  for (int o = 0; o < 64; ++o) {
    float v = acc[o];
    float q2 = v * v;
#pragma unroll
    for (int m = 32; m > 0; m >>= 1) {
      v  += __shfl_down(v, m);
      q2 += __shfl_down(q2, m);
    }
    if (lane == 0) { pS[wave*64 + o] = v; pQ[wave*64 + o] = q2; }
  }
  __syncthreads();
  if (t < 128) {
    int half = t >> 6, o = t & 63;
    float ts = pS[(half*2+0)*64 + o] + pS[(half*2+1)*64 + o];
    float tq = pQ[(half*2+0)*64 + o] + pQ[(half*2+1)*64 + o];
    part[(size_t)blockIdx.x*256 + t]       = ts;
    part[(size_t)blockIdx.x*256 + 128 + t] = tq;
  }
}

// ================== per-channel stats pass (layers 0/1) ==================
// block handles 2048 rows of Y[NROWS][64]; coalesced; partials to ws.
__global__ __launch_bounds__(256) void stats_kernel(const float* __restrict__ Y,
                                                    float* __restrict__ part)
{
  const int t = threadIdx.x;
  const int c = t & 63, g = t >> 6;
  const size_t base = (size_t)blockIdx.x * 2048;
  float s = 0.f, q = 0.f;
  for (int u = 0; u < 512; ++u) {
    size_t row = base + (size_t)(g + (u << 2));
    float v = Y[row*64 + c];
    s += v; q += v*v;
  }
  __shared__ float pS[256], pQ[256];
  pS[t] = s; pQ[t] = q;
  __syncthreads();
  if (t < 64) {
    float ts = pS[t] + pS[t+64] + pS[t+128] + pS[t+192];
    float tq = pQ[t] + pQ[t+64] + pQ[t+128] + pQ[t+192];
    part[(size_t)blockIdx.x*128 + t]      = ts;
    part[(size_t)blockIdx.x*128 + 64 + t] = tq;
  }
}

// deterministic tree reduce of block partials: sums[j] = sum_i part[i*stride+j]
__global__ __launch_bounds__(256) void reduce_kernel(const float* __restrict__ part,
                                                     int nb, int stride,
                                                     float* __restrict__ sums)
{
  const int j = blockIdx.x;
  const int t = threadIdx.x;
  float s = 0.f;
  for (int i = t; i < nb; i += 256) s += part[(size_t)i*stride + j];
  __shared__ float buf[256];
  buf[t] = s;
  __syncthreads();
  for (int m = 128; m > 0; m >>= 1) {
    if (t < m) buf[t] += buf[t + m];
    __syncthreads();
  }
  if (t == 0) sums[j] = buf[0];
}

// mean/var -> scale/shift
__global__ void finalize_kernel(const float* __restrict__ sums, int cout,
                                const float* __restrict__ g, const float* __restrict__ be,
                                float* __restrict__ scsh)
{
  int o = threadIdx.x;
  if (o < cout) {
    const float n = (float)NROWS;
    float mean = sums[o] / n;
    float var  = sums[cout + o] / n - mean*mean;
    float sc   = g[o] / sqrtf(var + 1e-5f);
    scsh[o]        = sc;
    scsh[cout + o] = be[o] - mean*sc;
  }
}

// final: BN2 + ReLU applied to max (or min if scale<0) over K
__global__ __launch_bounds__(256) void out_kernel(const float* __restrict__ Ymax,
                                                  const float* __restrict__ Ymin,
                                                  const float* __restrict__ scsh,
                                                  float* __restrict__ outx)
{
  const int e = blockIdx.x*256 + threadIdx.x;   // < 2097152 exactly
  const int o = e & 127;
  float sc = scsh[o], sh = scsh[128 + o];
  float v = (sc >= 0.f) ? Ymax[e] : Ymin[e];
  outx[e] = fmaxf(0.f, sc*v + sh);
}

// ============================ launcher ============================
extern "C" void kernel_launch(void* const* d_in, const int* in_sizes, int n_in,
                              void* d_out, int out_size, void* d_ws, size_t ws_size,
                              hipStream_t stream)
{
  (void)in_sizes; (void)n_in; (void)out_size; (void)ws_size;
  const float* xyz  = (const float*)d_in[0];
  const float* feat = (const float*)d_in[1];
  const float* W0 = (const float*)d_in[2];
  const float* b0 = (const float*)d_in[3];
  const float* g0 = (const float*)d_in[4];
  const float* e0 = (const float*)d_in[5];
  const float* W1 = (const float*)d_in[6];
  const float* b1 = (const float*)d_in[7];
  const float* g1 = (const float*)d_in[8];
  const float* e1 = (const float*)d_in[9];
  const float* W2 = (const float*)d_in[10];
  const float* b2 = (const float*)d_in[11];
  const float* g2 = (const float*)d_in[12];
  const float* e2 = (const float*)d_in[13];

  float* out_newxyz = (float*)d_out;                 // [16,1024,3]
  float* out_x      = (float*)d_out + BB*SS*3;       // [16,1024,128]

  // workspace layout (bytes)
  constexpr size_t OFF_IDX  = 0;                         // 524288 int  (2 MB)
  constexpr size_t OFF_Y    = 2097152;                   // 134 MB fp32
  constexpr size_t OFF_YMAX = OFF_Y    + 134217728;      // 8 MB
  constexpr size_t OFF_YMIN = OFF_YMAX + 8388608;        // 8 MB
  constexpr size_t OFF_PART = OFF_YMIN + 8388608;        // 4 MB (max partials)
  constexpr size_t OFF_SUMS = OFF_PART + 4194304;        // 3 x 1 KB
  constexpr size_t OFF_SCSH = OFF_SUMS + 3072;           // 3 x 1 KB

  char* ws = (char*)d_ws;
  int*   idxb  = (int*)  (ws + OFF_IDX);
  float* Y     = (float*)(ws + OFF_Y);
  float* Ymax  = (float*)(ws + OFF_YMAX);
  float* Ymin  = (float*)(ws + OFF_YMIN);
  float* part  = (float*)(ws + OFF_PART);
  float* sums0 = (float*)(ws + OFF_SUMS);
  float* sums1 = sums0 + 256;
  float* sums2 = sums1 + 256;
  float* scsh0 = (float*)(ws + OFF_SCSH);
  float* scsh1 = scsh0 + 256;
  float* scsh2 = scsh1 + 256;

  fps_kernel  <<<BB, 256, 0, stream>>>(xyz, out_newxyz);
  ballq_kernel<<<BB*SS/128, 128, 0, stream>>>(xyz, out_newxyz, idxb);

  layer0_kernel<<<NROWS/256, 256, 0, stream>>>(xyz, feat, out_newxyz, idxb, W0, b0, Y);
  stats_kernel <<<256, 256, 0, stream>>>(Y, part);
  reduce_kernel<<<128, 256, 0, stream>>>(part, 256, 128, sums0);
  finalize_kernel<<<1, 128, 0, stream>>>(sums0, 64, g0, e0, scsh0);

  layer1_kernel<<<NROWS/256, 256, 0, stream>>>(Y, W1, b1, scsh0, scsh0 + 64);
  stats_kernel <<<256, 256, 0, stream>>>(Y, part);
  reduce_kernel<<<128, 256, 0, stream>>>(part, 256, 128, sums1);
  finalize_kernel<<<1, 128, 0, stream>>>(sums1, 64, g1, e1, scsh1);

  layer2_kernel<<<NROWS*2/256, 256, 0, stream>>>(Y, W2, b2, scsh1, scsh1 + 64, Ymax, Ymin, part);
  reduce_kernel<<<256, 256, 0, stream>>>(part, 4096, 256, sums2);
  finalize_kernel<<<1, 128, 0, stream>>>(sums2, 128, g2, e2, scsh2);

  out_kernel<<<BB*SS*128/256, 256, 0, stream>>>(Ymax, Ymin, scsh2, out_x);
}

// Round 7
// 2231.618 us; speedup vs baseline: 9.8328x; 9.8328x over previous
//
#include <hip/hip_runtime.h>

#define BB 16
#define NN 4096
#define SS 1024
#define KK 32
#define NPT 1024
#define NS 32
#define NROWS (BB*SS*KK)   // 524288 rows; 32768 rows (2^15) per batch

// ============================= FPS =============================
// one block per batch; 256 threads x 16 points in registers.
__global__ __launch_bounds__(256) void fps_kernel(const float* __restrict__ xyz,
                                                  float* __restrict__ newxyz)
{
#pragma clang fp contract(off)
  const int b = blockIdx.x;
  const int t = threadIdx.x;
  const float* xb = xyz + (size_t)b * NN * 3;
  float px[16], py[16], pz[16], dist[16];
#pragma unroll
  for (int j = 0; j < 16; ++j) {
    const float* p = xb + (size_t)(t + j*256) * 3;
    px[j] = p[0]; py[j] = p[1]; pz[j] = p[2];
    dist[j] = 1e10f;
  }
  __shared__ float cx, cy, cz;
  __shared__ float wv[4];
  __shared__ int   wi[4];
  float* outb = newxyz + (size_t)b * NPT * 3;
  if (t == 0) {
    cx = px[0]; cy = py[0]; cz = pz[0];
    outb[0] = px[0]; outb[1] = py[0]; outb[2] = pz[0];
  }
  __syncthreads();
  for (int s = 0; s < NPT; ++s) {
    const float ccx = cx, ccy = cy, ccz = cz;
    float best = -1.0f; int bi = 0;
#pragma unroll
    for (int j = 0; j < 16; ++j) {
      float dx = px[j] - ccx;
      float dy = py[j] - ccy;
      float dz = pz[j] - ccz;
      float d = dx*dx;
      d = d + dy*dy;
      d = d + dz*dz;
      float dn = fminf(dist[j], d);
      dist[j] = dn;
      bool gt = dn > best;
      best = gt ? dn : best;
      bi   = gt ? (t + j*256) : bi;
    }
#pragma unroll
    for (int off = 32; off > 0; off >>= 1) {
      float ov = __shfl_down(best, off);
      int   oi = __shfl_down(bi, off);
      if (ov > best || (ov == best && oi < bi)) { best = ov; bi = oi; }
    }
    if ((t & 63) == 0) { wv[t >> 6] = best; wi[t >> 6] = bi; }
    __syncthreads();
    float fb = wv[0]; int fi = wi[0];
#pragma unroll
    for (int w = 1; w < 4; ++w) {
      float v = wv[w]; int i2 = wi[w];
      if (v > fb || (v == fb && i2 < fi)) { fb = v; fi = i2; }
    }
    if (s + 1 < NPT && t == (fi & 255)) {
      int jj = fi >> 8;
      float sx = 0.f, sy = 0.f, sz = 0.f;
#pragma unroll
      for (int j = 0; j < 16; ++j) if (jj == j) { sx = px[j]; sy = py[j]; sz = pz[j]; }
      cx = sx; cy = sy; cz = sz;
      outb[(size_t)(s+1)*3 + 0] = sx;
      outb[(size_t)(s+1)*3 + 1] = sy;
      outb[(size_t)(s+1)*3 + 2] = sz;
    }
    __syncthreads();
  }
}

// ============================ Ball query ============================
// wave per centroid (16 centroids/wave, 64/block). Batch xyz staged in LDS.
// Phase 1: ballot-compact in-ball candidates (dist<=r) into per-wave buffer
// (ascending point-index order == lax.top_k stable tie order).
// Phase 2: stable rank selection; rank>=cnt positions get rank-0 (nearest).
#define BQCAP 512
__global__ __launch_bounds__(256) void ballq_kernel(const float* __restrict__ xyz,
                                                    const float* __restrict__ newxyz,
                                                    int* __restrict__ idxout)
{
#pragma clang fp contract(off)
  __shared__ float sx[NN], sy[NN], sz[NN];
  __shared__ float bd[4][BQCAP];
  __shared__ int   bi_[4][BQCAP];
  __shared__ int   outw[4][32];
  const int t = threadIdx.x;
  const int b   = blockIdx.x >> 4;     // 16 blocks per batch
  const int sub = blockIdx.x & 15;     // 64 centroids per block
  for (int p = t; p < NN; p += 256) {
    const float* s = xyz + ((size_t)b * NN + p) * 3;
    sx[p] = s[0]; sy[p] = s[1]; sz[p] = s[2];
  }
  __syncthreads();
  const int w = t >> 6, lane = t & 63;
  const unsigned long long ltmask = (1ull << lane) - 1ull;
  for (int ci = 0; ci < 16; ++ci) {
    const int sidx = b * SS + sub * 64 + w * 16 + ci;
    const float cxv = newxyz[(size_t)sidx*3 + 0];
    const float cyv = newxyz[(size_t)sidx*3 + 1];
    const float czv = newxyz[(size_t)sidx*3 + 2];
    float sqc = cxv*cxv; sqc = sqc + cyv*cyv; sqc = sqc + czv*czv;
    int cnt = 0;
    for (int u = 0; u < NN/64; ++u) {
      const int p = u*64 + lane;
      float x = sx[p], y = sy[p], z = sz[p];
      float sqx = x*x; sqx = sqx + y*y; sqx = sqx + z*z;
      float dot = x*cxv; dot = dot + y*cyv; dot = dot + z*czv;
      float d2 = (sqc + sqx) - 2.0f*dot;
      float dist = sqrtf(fmaxf(d2, 0.0f));
      bool in = (dist <= 0.2f);
      unsigned long long mask = __ballot(in);
      int pos = cnt + __popcll(mask & ltmask);
      if (in && pos < BQCAP) { bd[w][pos] = dist; bi_[w][pos] = p; }
      cnt += __popcll(mask);
    }
    if (cnt > BQCAP) cnt = BQCAP;
    __syncthreads();
    for (int base = 0; base < cnt; base += 64) {
      const int e = base + lane;
      const bool valid = e < cnt;
      const float de = bd[w][valid ? e : 0];
      int rank = 0;
#pragma unroll 4
      for (int j = 0; j < cnt; ++j) {
        float dj = bd[w][j];
        rank += (dj < de || (dj == de && j < e)) ? 1 : 0;
      }
      if (valid && rank < 32) outw[w][rank] = bi_[w][e];
    }
    __syncthreads();
    if (lane < 32) {
      int v = outw[w][(lane < cnt) ? lane : 0];
      idxout[(size_t)sidx * NS + lane] = v;
    }
    __syncthreads();
  }
}

// ===================== MLP layers: register-tiled GEMM =====================
// Block = 128 rows x COUT couts, 256 threads. X staged TRANSPOSED in LDS
// (Xt[k][row], pad 132 -> bank-clean), W transposed (Wt[k][cout]).
// BN batch-stats (sum, sumsq per cout) fused into epilogue as block partials.

// ---- Layer 0: gather + concat + conv(67->64). Xt c: 0..63 feat, 64..66 gxyz.
__global__ __launch_bounds__(256, 2) void layer0_kernel(
    const float* __restrict__ xyz, const float* __restrict__ feat,
    const float* __restrict__ newxyz, const int* __restrict__ idx,
    const float* __restrict__ W, const float* __restrict__ bias,
    float* __restrict__ Y, float* __restrict__ part)
{
  __shared__ __align__(16) float Xt[67][132];
  __shared__ __align__(16) float Wt[67][68];
  __shared__ float pS[4][64], pQ[4][64];
  const int t = threadIdx.x;
  for (int u = t; u < 67*64; u += 256) {
    int k = u >> 6, c = u & 63;
    Wt[k][c] = W[c*67 + (k < 64 ? 3 + k : k - 64)];
  }
  {
    const int row = t >> 1, half = t & 1;
    const int grow = blockIdx.x*128 + row;
    const int bs = grow >> 5;
    const int b  = grow >> 15;
    const int i  = idx[grow];
    const float* fp = feat + ((size_t)b*NN + i)*64 + half*32;
#pragma unroll
    for (int u = 0; u < 8; ++u) {
      float4 v = *(const float4*)(fp + u*4);
      int c = half*32 + u*4;
      Xt[c+0][row] = v.x; Xt[c+1][row] = v.y; Xt[c+2][row] = v.z; Xt[c+3][row] = v.w;
    }
    if (half) {
      const float* xp = xyz + ((size_t)b*NN + i)*3;
      const float* cp = newxyz + (size_t)bs*3;
      Xt[64][row] = xp[0]-cp[0]; Xt[65][row] = xp[1]-cp[1]; Xt[66][row] = xp[2]-cp[2];
    }
  }
  __syncthreads();
  const int w = t >> 6, rg = (t >> 3) & 7, cg = t & 7;
  const int r0 = w*32 + rg*4;
  float acc[4][8];
  {
    float4 b0 = *(const float4*)(bias + cg*8);
    float4 b1 = *(const float4*)(bias + cg*8 + 4);
#pragma unroll
    for (int i = 0; i < 4; ++i) {
      acc[i][0]=b0.x; acc[i][1]=b0.y; acc[i][2]=b0.z; acc[i][3]=b0.w;
      acc[i][4]=b1.x; acc[i][5]=b1.y; acc[i][6]=b1.z; acc[i][7]=b1.w;
    }
  }
  for (int k = 0; k < 67; ++k) {
    float4 a  = *(const float4*)&Xt[k][r0];
    float4 w0 = *(const float4*)&Wt[k][cg*8];
    float4 w1 = *(const float4*)&Wt[k][cg*8+4];
    float av[4] = {a.x, a.y, a.z, a.w};
    float bv[8] = {w0.x,w0.y,w0.z,w0.w,w1.x,w1.y,w1.z,w1.w};
#pragma unroll
    for (int i = 0; i < 4; ++i)
#pragma unroll
      for (int j = 0; j < 8; ++j) acc[i][j] += av[i]*bv[j];
  }
  const int growbase = blockIdx.x*128 + r0;
#pragma unroll
  for (int i = 0; i < 4; ++i) {
    float* yr = Y + (size_t)(growbase + i)*64 + cg*8;
    *(float4*)(yr)   = make_float4(acc[i][0],acc[i][1],acc[i][2],acc[i][3]);
    *(float4*)(yr+4) = make_float4(acc[i][4],acc[i][5],acc[i][6],acc[i][7]);
  }
  float s[8], q[8];
#pragma unroll
  for (int j = 0; j < 8; ++j) {
    s[j] = acc[0][j]+acc[1][j]+acc[2][j]+acc[3][j];
    q[j] = acc[0][j]*acc[0][j]+acc[1][j]*acc[1][j]+acc[2][j]*acc[2][j]+acc[3][j]*acc[3][j];
  }
#pragma unroll
  for (int m = 8; m <= 32; m <<= 1)
#pragma unroll
    for (int j = 0; j < 8; ++j) { s[j] += __shfl_xor(s[j], m); q[j] += __shfl_xor(q[j], m); }
  if ((t & 56) == 0) {
#pragma unroll
    for (int j = 0; j < 8; ++j) { pS[w][cg*8+j] = s[j]; pQ[w][cg*8+j] = q[j]; }
  }
  __syncthreads();
  if (t < 128) {
    int c = t & 63;
    if (t < 64) part[(size_t)blockIdx.x*128 + t] = pS[0][c]+pS[1][c]+pS[2][c]+pS[3][c];
    else        part[(size_t)blockIdx.x*128 + t] = pQ[0][c]+pQ[1][c]+pQ[2][c]+pQ[3][c];
  }
}

// ---- Layer 1: BN0+ReLU on stage, conv(64->64), in-place Y.
__global__ __launch_bounds__(256, 2) void layer1_kernel(
    float* __restrict__ Y,
    const float* __restrict__ W, const float* __restrict__ bias,
    const float* __restrict__ sc, const float* __restrict__ sh,
    float* __restrict__ part)
{
  __shared__ __align__(16) float Xt[64][132];
  __shared__ __align__(16) float Wt[64][68];
  __shared__ float pS[4][64], pQ[4][64];
  const int t = threadIdx.x;
  for (int u = t; u < 64*64; u += 256) {
    int k = u >> 6, c = u & 63;
    Wt[k][c] = W[c*64 + k];
  }
  {
    const int row = t >> 1, half = t & 1;
    const int grow = blockIdx.x*128 + row;
    const float* yp = Y + (size_t)grow*64 + half*32;
#pragma unroll
    for (int u = 0; u < 8; ++u) {
      float4 v = *(const float4*)(yp + u*4);
      int c = half*32 + u*4;
      float4 scv = *(const float4*)(sc + c);
      float4 shv = *(const float4*)(sh + c);
      Xt[c+0][row] = fmaxf(0.f, scv.x*v.x + shv.x);
      Xt[c+1][row] = fmaxf(0.f, scv.y*v.y + shv.y);
      Xt[c+2][row] = fmaxf(0.f, scv.z*v.z + shv.z);
      Xt[c+3][row] = fmaxf(0.f, scv.w*v.w + shv.w);
    }
  }
  __syncthreads();
  const int w = t >> 6, rg = (t >> 3) & 7, cg = t & 7;
  const int r0 = w*32 + rg*4;
  float acc[4][8];
  {
    float4 b0 = *(const float4*)(bias + cg*8);
    float4 b1 = *(const float4*)(bias + cg*8 + 4);
#pragma unroll
    for (int i = 0; i < 4; ++i) {
      acc[i][0]=b0.x; acc[i][1]=b0.y; acc[i][2]=b0.z; acc[i][3]=b0.w;
      acc[i][4]=b1.x; acc[i][5]=b1.y; acc[i][6]=b1.z; acc[i][7]=b1.w;
    }
  }
  for (int k = 0; k < 64; ++k) {
    float4 a  = *(const float4*)&Xt[k][r0];
    float4 w0 = *(const float4*)&Wt[k][cg*8];
    float4 w1 = *(const float4*)&Wt[k][cg*8+4];
    float av[4] = {a.x, a.y, a.z, a.w};
    float bv[8] = {w0.x,w0.y,w0.z,w0.w,w1.x,w1.y,w1.z,w1.w};
#pragma unroll
    for (int i = 0; i < 4; ++i)
#pragma unroll
      for (int j = 0; j < 8; ++j) acc[i][j] += av[i]*bv[j];
  }
  const int growbase = blockIdx.x*128 + r0;
#pragma unroll
  for (int i = 0; i < 4; ++i) {
    float* yr = Y + (size_t)(growbase + i)*64 + cg*8;
    *(float4*)(yr)   = make_float4(acc[i][0],acc[i][1],acc[i][2],acc[i][3]);
    *(float4*)(yr+4) = make_float4(acc[i][4],acc[i][5],acc[i][6],acc[i][7]);
  }
  float s[8], q[8];
#pragma unroll
  for (int j = 0; j < 8; ++j) {
    s[j] = acc[0][j]+acc[1][j]+acc[2][j]+acc[3][j];
    q[j] = acc[0][j]*acc[0][j]+acc[1][j]*acc[1][j]+acc[2][j]*acc[2][j]+acc[3][j]*acc[3][j];
  }
#pragma unroll
  for (int m = 8; m <= 32; m <<= 1)
#pragma unroll
    for (int j = 0; j < 8; ++j) { s[j] += __shfl_xor(s[j], m); q[j] += __shfl_xor(q[j], m); }
  if ((t & 56) == 0) {
#pragma unroll
    for (int j = 0; j < 8; ++j) { pS[w][cg*8+j] = s[j]; pQ[w][cg*8+j] = q[j]; }
  }
  __syncthreads();
  if (t < 128) {
    int c = t & 63;
    if (t < 64) part[(size_t)blockIdx.x*128 + t] = pS[0][c]+pS[1][c]+pS[2][c]+pS[3][c];
    else        part[(size_t)blockIdx.x*128 + t] = pQ[0][c]+pQ[1][c]+pQ[2][c]+pQ[3][c];
  }
}

// ---- Layer 2: BN1+ReLU on stage, conv(64->128), max/min over K epilogue.
// h = t>>7 selects cout half; thread tile 8 rows x 8 couts (acc 64).
// Block = 128 rows = 4 points; wave covers (h, 2 points).
__global__ __launch_bounds__(256, 2) void layer2_kernel(
    const float* __restrict__ Y,
    const float* __restrict__ W, const float* __restrict__ bias,
    const float* __restrict__ sc, const float* __restrict__ sh,
    float* __restrict__ Ymax, float* __restrict__ Ymin,
    float* __restrict__ part)
{
  __shared__ __align__(16) float Xt[64][132];
  __shared__ __align__(16) float Wt[64][132];
  __shared__ float pS[4][64], pQ[4][64];
  const int t = threadIdx.x;
  for (int u = t; u < 64*128; u += 256) {
    int k = u >> 7, c = u & 127;
    Wt[k][c] = W[c*64 + k];
  }
  {
    const int row = t >> 1, half = t & 1;
    const int grow = blockIdx.x*128 + row;
    const float* yp = Y + (size_t)grow*64 + half*32;
#pragma unroll
    for (int u = 0; u < 8; ++u) {
      float4 v = *(const float4*)(yp + u*4);
      int c = half*32 + u*4;
      float4 scv = *(const float4*)(sc + c);
      float4 shv = *(const float4*)(sh + c);
      Xt[c+0][row] = fmaxf(0.f, scv.x*v.x + shv.x);
      Xt[c+1][row] = fmaxf(0.f, scv.y*v.y + shv.y);
      Xt[c+2][row] = fmaxf(0.f, scv.z*v.z + shv.z);
      Xt[c+3][row] = fmaxf(0.f, scv.w*v.w + shv.w);
    }
  }
  __syncthreads();
  const int h = t >> 7, s7 = t & 127;
  const int rg = s7 >> 3, cg = s7 & 7;     // rg 0..15 (8 rows each)
  const int r0 = rg*8;
  float acc[8][8];
  {
    float4 b0 = *(const float4*)(bias + h*64 + cg*8);
    float4 b1 = *(const float4*)(bias + h*64 + cg*8 + 4);
#pragma unroll
    for (int i = 0; i < 8; ++i) {
      acc[i][0]=b0.x; acc[i][1]=b0.y; acc[i][2]=b0.z; acc[i][3]=b0.w;
      acc[i][4]=b1.x; acc[i][5]=b1.y; acc[i][6]=b1.z; acc[i][7]=b1.w;
    }
  }
  for (int k = 0; k < 64; ++k) {
    float4 a0 = *(const float4*)&Xt[k][r0];
    float4 a1 = *(const float4*)&Xt[k][r0+4];
    float4 w0 = *(const float4*)&Wt[k][h*64 + cg*8];
    float4 w1 = *(const float4*)&Wt[k][h*64 + cg*8 + 4];
    float av[8] = {a0.x,a0.y,a0.z,a0.w,a1.x,a1.y,a1.z,a1.w};
    float bv[8] = {w0.x,w0.y,w0.z,w0.w,w1.x,w1.y,w1.z,w1.w};
#pragma unroll
    for (int i = 0; i < 8; ++i)
#pragma unroll
      for (int j = 0; j < 8; ++j) acc[i][j] += av[i]*bv[j];
  }
  const int w = t >> 6, lane = t & 63;
  // max/min over the 32 rows of each point (8 local + xor over rg bits 0,1)
  float mx[8], mn[8];
#pragma unroll
  for (int j = 0; j < 8; ++j) {
    float a = acc[0][j], bsm = acc[0][j];
#pragma unroll
    for (int i = 1; i < 8; ++i) { a = fmaxf(a, acc[i][j]); bsm = fminf(bsm, acc[i][j]); }
    mx[j] = a; mn[j] = bsm;
  }
#pragma unroll
  for (int m = 8; m <= 16; m <<= 1)
#pragma unroll
    for (int j = 0; j < 8; ++j) {
      mx[j] = fmaxf(mx[j], __shfl_xor(mx[j], m));
      mn[j] = fminf(mn[j], __shfl_xor(mn[j], m));
    }
  if ((lane & 24) == 0) {
    const int p = (w & 1)*2 + (lane >> 5);
    const size_t bs = (size_t)blockIdx.x*4 + p;
    float* dmx = Ymax + bs*128 + h*64 + cg*8;
    float* dmn = Ymin + bs*128 + h*64 + cg*8;
    *(float4*)(dmx)   = make_float4(mx[0],mx[1],mx[2],mx[3]);
    *(float4*)(dmx+4) = make_float4(mx[4],mx[5],mx[6],mx[7]);
    *(float4*)(dmn)   = make_float4(mn[0],mn[1],mn[2],mn[3]);
    *(float4*)(dmn+4) = make_float4(mn[4],mn[5],mn[6],mn[7]);
  }
  float s[8], q[8];
#pragma unroll
  for (int j = 0; j < 8; ++j) {
    float ts = 0.f, tq = 0.f;
#pragma unroll
    for (int i = 0; i < 8; ++i) { ts += acc[i][j]; tq += acc[i][j]*acc[i][j]; }
    s[j] = ts; q[j] = tq;
  }
#pragma unroll
  for (int m = 8; m <= 32; m <<= 1)
#pragma unroll
    for (int j = 0; j < 8; ++j) { s[j] += __shfl_xor(s[j], m); q[j] += __shfl_xor(q[j], m); }
  if ((lane & 56) == 0) {
#pragma unroll
    for (int j = 0; j < 8; ++j) { pS[w][cg*8+j] = s[j]; pQ[w][cg*8+j] = q[j]; }
  }
  __syncthreads();
  if (t < 128) {
    int c = t & 63, h2 = t >> 6;
    part[(size_t)blockIdx.x*256 + h2*64 + c]       = pS[2*h2][c] + pS[2*h2+1][c];
    part[(size_t)blockIdx.x*256 + 128 + h2*64 + c] = pQ[2*h2][c] + pQ[2*h2+1][c];
  }
}

// ============ deterministic tree reduce of block partials ============
__global__ __launch_bounds__(256) void reduce_kernel(const float* __restrict__ part,
                                                     int nb, int stride,
                                                     float* __restrict__ sums)
{
  const int j = blockIdx.x;
  const int t = threadIdx.x;
  float s = 0.f;
  for (int i = t; i < nb; i += 256) s += part[(size_t)i*stride + j];
  __shared__ float buf[256];
  buf[t] = s;
  __syncthreads();
  for (int m = 128; m > 0; m >>= 1) {
    if (t < m) buf[t] += buf[t + m];
    __syncthreads();
  }
  if (t == 0) sums[j] = buf[0];
}

__global__ void finalize_kernel(const float* __restrict__ sums, int cout,
                                const float* __restrict__ g, const float* __restrict__ be,
                                float* __restrict__ scsh)
{
  int o = threadIdx.x;
  if (o < cout) {
    const float n = (float)NROWS;
    float mean = sums[o] / n;
    float var  = sums[cout + o] / n - mean*mean;
    float sc   = g[o] / sqrtf(var + 1e-5f);
    scsh[o]        = sc;
    scsh[cout + o] = be[o] - mean*sc;
  }
}

__global__ __launch_bounds__(256) void out_kernel(const float* __restrict__ Ymax,
                                                  const float* __restrict__ Ymin,
                                                  const float* __restrict__ scsh,
                                                  float* __restrict__ outx)
{
  const int e = blockIdx.x*256 + threadIdx.x;
  const int o = e & 127;
  float sc = scsh[o], sh = scsh[128 + o];
  float v = (sc >= 0.f) ? Ymax[e] : Ymin[e];
  outx[e] = fmaxf(0.f, sc*v + sh);
}

// ============================ launcher ============================
extern "C" void kernel_launch(void* const* d_in, const int* in_sizes, int n_in,
                              void* d_out, int out_size, void* d_ws, size_t ws_size,
                              hipStream_t stream)
{
  (void)in_sizes; (void)n_in; (void)out_size; (void)ws_size;
  const float* xyz  = (const float*)d_in[0];
  const float* feat = (const float*)d_in[1];
  const float* W0 = (const float*)d_in[2];
  const float* b0 = (const float*)d_in[3];
  const float* g0 = (const float*)d_in[4];
  const float* e0 = (const float*)d_in[5];
  const float* W1 = (const float*)d_in[6];
  const float* b1 = (const float*)d_in[7];
  const float* g1 = (const float*)d_in[8];
  const float* e1 = (const float*)d_in[9];
  const float* W2 = (const float*)d_in[10];
  const float* b2 = (const float*)d_in[11];
  const float* g2 = (const float*)d_in[12];
  const float* e2 = (const float*)d_in[13];

  float* out_newxyz = (float*)d_out;
  float* out_x      = (float*)d_out + BB*SS*3;

  constexpr size_t OFF_IDX  = 0;                         // 2 MB
  constexpr size_t OFF_Y    = 2097152;                   // 134 MB
  constexpr size_t OFF_YMAX = OFF_Y    + 134217728;      // 8 MB
  constexpr size_t OFF_YMIN = OFF_YMAX + 8388608;        // 8 MB
  constexpr size_t OFF_PART = OFF_YMIN + 8388608;        // 4 MB
  constexpr size_t OFF_SUMS = OFF_PART + 4194304;
  constexpr size_t OFF_SCSH = OFF_SUMS + 3072;

  char* ws = (char*)d_ws;
  int*   idxb  = (int*)  (ws + OFF_IDX);
  float* Y     = (float*)(ws + OFF_Y);
  float* Ymax  = (float*)(ws + OFF_YMAX);
  float* Ymin  = (float*)(ws + OFF_YMIN);
  float* part  = (float*)(ws + OFF_PART);
  float* sums0 = (float*)(ws + OFF_SUMS);
  float* sums1 = sums0 + 256;
  float* sums2 = sums1 + 256;
  float* scsh0 = (float*)(ws + OFF_SCSH);
  float* scsh1 = scsh0 + 256;
  float* scsh2 = scsh1 + 256;

  fps_kernel  <<<BB, 256, 0, stream>>>(xyz, out_newxyz);
  ballq_kernel<<<256, 256, 0, stream>>>(xyz, out_newxyz, idxb);

  layer0_kernel<<<NROWS/128, 256, 0, stream>>>(xyz, feat, out_newxyz, idxb, W0, b0, Y, part);
  reduce_kernel<<<128, 256, 0, stream>>>(part, NROWS/128, 128, sums0);
  finalize_kernel<<<1, 128, 0, stream>>>(sums0, 64, g0, e0, scsh0);

  layer1_kernel<<<NROWS/128, 256, 0, stream>>>(Y, W1, b1, scsh0, scsh0 + 64, part);
  reduce_kernel<<<128, 256, 0, stream>>>(part, NROWS/128, 128, sums1);
  finalize_kernel<<<1, 128, 0, stream>>>(sums1, 64, g1, e1, scsh1);

  layer2_kernel<<<NROWS/128, 256, 0, stream>>>(Y, W2, b2, scsh1, scsh1 + 64, Ymax, Ymin, part);
  reduce_kernel<<<256, 256, 0, stream>>>(part, NROWS/128, 256, sums2);
  finalize_kernel<<<1, 128, 0, stream>>>(sums2, 128, g2, e2, scsh2);

  out_kernel<<<BB*SS*128/256, 256, 0, stream>>>(Ymax, Ymin, scsh2, out_x);
}

// Round 8
// 1940.532 us; speedup vs baseline: 11.3077x; 1.1500x over previous
//
#include <hip/hip_runtime.h>

#define BB 16
#define NN 4096
#define SS 1024
#define KK 32
#define NPT 1024
#define NS 32
#define NROWS (BB*SS*KK)   // 524288 rows; 32768 rows (2^15) per batch

// ============================= FPS =============================
// one block per batch; 256 threads x 16 points in registers.
// v2: xyz staged in LDS -> center broadcast is a same-address LDS read by all
// threads (no winner-publish hop), ONE barrier/step with parity-double-buffered
// wave candidates. Arithmetic identical to v1 (contract off, same op order).
__global__ __launch_bounds__(256) void fps_kernel(const float* __restrict__ xyz,
                                                  float* __restrict__ newxyz)
{
#pragma clang fp contract(off)
  __shared__ float sx[NN], sy[NN], sz[NN];
  __shared__ float wv[2][4];
  __shared__ int   wi[2][4];
  const int b = blockIdx.x;
  const int t = threadIdx.x;
  const float* xb = xyz + (size_t)b * NN * 3;
  // stage coords to LDS (coalesced global reads, one-time)
  for (int e = t; e < NN*3; e += 256) {
    int pt = e / 3, comp = e - pt*3;
    float v = xb[e];
    if (comp == 0) sx[pt] = v; else if (comp == 1) sy[pt] = v; else sz[pt] = v;
  }
  __syncthreads();
  float px[16], py[16], pz[16], dist[16];
#pragma unroll
  for (int j = 0; j < 16; ++j) {
    px[j] = sx[t + j*256]; py[j] = sy[t + j*256]; pz[j] = sz[t + j*256];
    dist[j] = 1e10f;
  }
  float ccx = sx[0], ccy = sy[0], ccz = sz[0];
  float* outb = newxyz + (size_t)b * NPT * 3;
  if (t == 0) { outb[0] = ccx; outb[1] = ccy; outb[2] = ccz; }
  const int w = t >> 6, lane = t & 63;
  for (int s = 0; s < NPT; ++s) {
    float best = -1.0f; int bi = 0;
#pragma unroll
    for (int j = 0; j < 16; ++j) {
      float dx = px[j] - ccx;
      float dy = py[j] - ccy;
      float dz = pz[j] - ccz;
      float d = dx*dx;
      d = d + dy*dy;
      d = d + dz*dz;
      float dn = fminf(dist[j], d);
      dist[j] = dn;
      bool gt = dn > best;           // strict > keeps lowest index on ties
      best = gt ? dn : best;
      bi   = gt ? (t + j*256) : bi;
    }
#pragma unroll
    for (int off = 32; off > 0; off >>= 1) {
      float ov = __shfl_down(best, off);
      int   oi = __shfl_down(bi, off);
      if (ov > best || (ov == best && oi < bi)) { best = ov; bi = oi; }
    }
    const int par = s & 1;
    if (lane == 0) { wv[par][w] = best; wi[par][w] = bi; }
    __syncthreads();
    float fb = wv[par][0]; int fi = wi[par][0];
#pragma unroll
    for (int q = 1; q < 4; ++q) {
      float v = wv[par][q]; int i2 = wi[par][q];
      if (v > fb || (v == fb && i2 < fi)) { fb = v; fi = i2; }
    }
    ccx = sx[fi]; ccy = sy[fi]; ccz = sz[fi];   // broadcast read, no conflict
    if (t == 0 && s + 1 < NPT) {
      outb[(size_t)(s+1)*3 + 0] = ccx;
      outb[(size_t)(s+1)*3 + 1] = ccy;
      outb[(size_t)(s+1)*3 + 2] = ccz;
    }
  }
}

// ============================ Ball query ============================
// wave per centroid (16 centroids/wave, 64/block). Batch xyz staged in LDS.
// Phase 1: ballot-compact in-ball candidates (dist<=r) into per-wave buffer
// (ascending point-index order == lax.top_k stable tie order).
// Phase 2: stable rank selection; rank>=cnt positions get rank-0 (nearest).
#define BQCAP 512
__global__ __launch_bounds__(256) void ballq_kernel(const float* __restrict__ xyz,
                                                    const float* __restrict__ newxyz,
                                                    int* __restrict__ idxout)
{
#pragma clang fp contract(off)
  __shared__ float sx[NN], sy[NN], sz[NN];
  __shared__ float bd[4][BQCAP];
  __shared__ int   bi_[4][BQCAP];
  __shared__ int   outw[4][32];
  const int t = threadIdx.x;
  const int b   = blockIdx.x >> 4;     // 16 blocks per batch
  const int sub = blockIdx.x & 15;     // 64 centroids per block
  for (int p = t; p < NN; p += 256) {
    const float* s = xyz + ((size_t)b * NN + p) * 3;
    sx[p] = s[0]; sy[p] = s[1]; sz[p] = s[2];
  }
  __syncthreads();
  const int w = t >> 6, lane = t & 63;
  const unsigned long long ltmask = (1ull << lane) - 1ull;
  for (int ci = 0; ci < 16; ++ci) {
    const int sidx = b * SS + sub * 64 + w * 16 + ci;
    const float cxv = newxyz[(size_t)sidx*3 + 0];
    const float cyv = newxyz[(size_t)sidx*3 + 1];
    const float czv = newxyz[(size_t)sidx*3 + 2];
    float sqc = cxv*cxv; sqc = sqc + cyv*cyv; sqc = sqc + czv*czv;
    int cnt = 0;
    for (int u = 0; u < NN/64; ++u) {
      const int p = u*64 + lane;
      float x = sx[p], y = sy[p], z = sz[p];
      float sqx = x*x; sqx = sqx + y*y; sqx = sqx + z*z;
      float dot = x*cxv; dot = dot + y*cyv; dot = dot + z*czv;
      float d2 = (sqc + sqx) - 2.0f*dot;
      float dist = sqrtf(fmaxf(d2, 0.0f));
      bool in = (dist <= 0.2f);
      unsigned long long mask = __ballot(in);
      int pos = cnt + __popcll(mask & ltmask);
      if (in && pos < BQCAP) { bd[w][pos] = dist; bi_[w][pos] = p; }
      cnt += __popcll(mask);
    }
    if (cnt > BQCAP) cnt = BQCAP;
    __syncthreads();
    for (int base = 0; base < cnt; base += 64) {
      const int e = base + lane;
      const bool valid = e < cnt;
      const float de = bd[w][valid ? e : 0];
      int rank = 0;
#pragma unroll 4
      for (int j = 0; j < cnt; ++j) {
        float dj = bd[w][j];
        rank += (dj < de || (dj == de && j < e)) ? 1 : 0;
      }
      if (valid && rank < 32) outw[w][rank] = bi_[w][e];
    }
    __syncthreads();
    if (lane < 32) {
      int v = outw[w][(lane < cnt) ? lane : 0];
      idxout[(size_t)sidx * NS + lane] = v;
    }
    __syncthreads();
  }
}

// ===================== MLP layers: register-tiled GEMM =====================
// Block = 128 rows x COUT couts, 256 threads. X staged TRANSPOSED in LDS
// (Xt[k][row], pad 132 -> bank-clean), W transposed (Wt[k][cout]).
// BN batch-stats (sum, sumsq per cout) fused into epilogue as block partials.

// ---- Layer 0: gather + concat + conv(67->64). Xt c: 0..63 feat, 64..66 gxyz.
__global__ __launch_bounds__(256, 2) void layer0_kernel(
    const float* __restrict__ xyz, const float* __restrict__ feat,
    const float* __restrict__ newxyz, const int* __restrict__ idx,
    const float* __restrict__ W, const float* __restrict__ bias,
    float* __restrict__ Y, float* __restrict__ part)
{
  __shared__ __align__(16) float Xt[67][132];
  __shared__ __align__(16) float Wt[67][68];
  __shared__ float pS[4][64], pQ[4][64];
  const int t = threadIdx.x;
  for (int u = t; u < 67*64; u += 256) {
    int k = u >> 6, c = u & 63;
    Wt[k][c] = W[c*67 + (k < 64 ? 3 + k : k - 64)];
  }
  {
    const int row = t >> 1, half = t & 1;
    const int grow = blockIdx.x*128 + row;
    const int bs = grow >> 5;
    const int b  = grow >> 15;
    const int i  = idx[grow];
    const float* fp = feat + ((size_t)b*NN + i)*64 + half*32;
#pragma unroll
    for (int u = 0; u < 8; ++u) {
      float4 v = *(const float4*)(fp + u*4);
      int c = half*32 + u*4;
      Xt[c+0][row] = v.x; Xt[c+1][row] = v.y; Xt[c+2][row] = v.z; Xt[c+3][row] = v.w;
    }
    if (half) {
      const float* xp = xyz + ((size_t)b*NN + i)*3;
      const float* cp = newxyz + (size_t)bs*3;
      Xt[64][row] = xp[0]-cp[0]; Xt[65][row] = xp[1]-cp[1]; Xt[66][row] = xp[2]-cp[2];
    }
  }
  __syncthreads();
  const int w = t >> 6, rg = (t >> 3) & 7, cg = t & 7;
  const int r0 = w*32 + rg*4;
  float acc[4][8];
  {
    float4 b0 = *(const float4*)(bias + cg*8);
    float4 b1 = *(const float4*)(bias + cg*8 + 4);
#pragma unroll
    for (int i = 0; i < 4; ++i) {
      acc[i][0]=b0.x; acc[i][1]=b0.y; acc[i][2]=b0.z; acc[i][3]=b0.w;
      acc[i][4]=b1.x; acc[i][5]=b1.y; acc[i][6]=b1.z; acc[i][7]=b1.w;
    }
  }
  for (int k = 0; k < 67; ++k) {
    float4 a  = *(const float4*)&Xt[k][r0];
    float4 w0 = *(const float4*)&Wt[k][cg*8];
    float4 w1 = *(const float4*)&Wt[k][cg*8+4];
    float av[4] = {a.x, a.y, a.z, a.w};
    float bv[8] = {w0.x,w0.y,w0.z,w0.w,w1.x,w1.y,w1.z,w1.w};
#pragma unroll
    for (int i = 0; i < 4; ++i)
#pragma unroll
      for (int j = 0; j < 8; ++j) acc[i][j] += av[i]*bv[j];
  }
  const int growbase = blockIdx.x*128 + r0;
#pragma unroll
  for (int i = 0; i < 4; ++i) {
    float* yr = Y + (size_t)(growbase + i)*64 + cg*8;
    *(float4*)(yr)   = make_float4(acc[i][0],acc[i][1],acc[i][2],acc[i][3]);
    *(float4*)(yr+4) = make_float4(acc[i][4],acc[i][5],acc[i][6],acc[i][7]);
  }
  float s[8], q[8];
#pragma unroll
  for (int j = 0; j < 8; ++j) {
    s[j] = acc[0][j]+acc[1][j]+acc[2][j]+acc[3][j];
    q[j] = acc[0][j]*acc[0][j]+acc[1][j]*acc[1][j]+acc[2][j]*acc[2][j]+acc[3][j]*acc[3][j];
  }
#pragma unroll
  for (int m = 8; m <= 32; m <<= 1)
#pragma unroll
    for (int j = 0; j < 8; ++j) { s[j] += __shfl_xor(s[j], m); q[j] += __shfl_xor(q[j], m); }
  if ((t & 56) == 0) {
#pragma unroll
    for (int j = 0; j < 8; ++j) { pS[w][cg*8+j] = s[j]; pQ[w][cg*8+j] = q[j]; }
  }
  __syncthreads();
  if (t < 128) {
    int c = t & 63;
    if (t < 64) part[(size_t)blockIdx.x*128 + t] = pS[0][c]+pS[1][c]+pS[2][c]+pS[3][c];
    else        part[(size_t)blockIdx.x*128 + t] = pQ[0][c]+pQ[1][c]+pQ[2][c]+pQ[3][c];
  }
}

// ---- Layer 1: BN0+ReLU on stage, conv(64->64), in-place Y.
__global__ __launch_bounds__(256, 2) void layer1_kernel(
    float* __restrict__ Y,
    const float* __restrict__ W, const float* __restrict__ bias,
    const float* __restrict__ sc, const float* __restrict__ sh,
    float* __restrict__ part)
{
  __shared__ __align__(16) float Xt[64][132];
  __shared__ __align__(16) float Wt[64][68];
  __shared__ float pS[4][64], pQ[4][64];
  const int t = threadIdx.x;
  for (int u = t; u < 64*64; u += 256) {
    int k = u >> 6, c = u & 63;
    Wt[k][c] = W[c*64 + k];
  }
  {
    const int row = t >> 1, half = t & 1;
    const int grow = blockIdx.x*128 + row;
    const float* yp = Y + (size_t)grow*64 + half*32;
#pragma unroll
    for (int u = 0; u < 8; ++u) {
      float4 v = *(const float4*)(yp + u*4);
      int c = half*32 + u*4;
      float4 scv = *(const float4*)(sc + c);
      float4 shv = *(const float4*)(sh + c);
      Xt[c+0][row] = fmaxf(0.f, scv.x*v.x + shv.x);
      Xt[c+1][row] = fmaxf(0.f, scv.y*v.y + shv.y);
      Xt[c+2][row] = fmaxf(0.f, scv.z*v.z + shv.z);
      Xt[c+3][row] = fmaxf(0.f, scv.w*v.w + shv.w);
    }
  }
  __syncthreads();
  const int w = t >> 6, rg = (t >> 3) & 7, cg = t & 7;
  const int r0 = w*32 + rg*4;
  float acc[4][8];
  {
    float4 b0 = *(const float4*)(bias + cg*8);
    float4 b1 = *(const float4*)(bias + cg*8 + 4);
#pragma unroll
    for (int i = 0; i < 4; ++i) {
      acc[i][0]=b0.x; acc[i][1]=b0.y; acc[i][2]=b0.z; acc[i][3]=b0.w;
      acc[i][4]=b1.x; acc[i][5]=b1.y; acc[i][6]=b1.z; acc[i][7]=b1.w;
    }
  }
  for (int k = 0; k < 64; ++k) {
    float4 a  = *(const float4*)&Xt[k][r0];
    float4 w0 = *(const float4*)&Wt[k][cg*8];
    float4 w1 = *(const float4*)&Wt[k][cg*8+4];
    float av[4] = {a.x, a.y, a.z, a.w};
    float bv[8] = {w0.x,w0.y,w0.z,w0.w,w1.x,w1.y,w1.z,w1.w};
#pragma unroll
    for (int i = 0; i < 4; ++i)
#pragma unroll
      for (int j = 0; j < 8; ++j) acc[i][j] += av[i]*bv[j];
  }
  const int growbase = blockIdx.x*128 + r0;
#pragma unroll
  for (int i = 0; i < 4; ++i) {
    float* yr = Y + (size_t)(growbase + i)*64 + cg*8;
    *(float4*)(yr)   = make_float4(acc[i][0],acc[i][1],acc[i][2],acc[i][3]);
    *(float4*)(yr+4) = make_float4(acc[i][4],acc[i][5],acc[i][6],acc[i][7]);
  }
  float s[8], q[8];
#pragma unroll
  for (int j = 0; j < 8; ++j) {
    s[j] = acc[0][j]+acc[1][j]+acc[2][j]+acc[3][j];
    q[j] = acc[0][j]*acc[0][j]+acc[1][j]*acc[1][j]+acc[2][j]*acc[2][j]+acc[3][j]*acc[3][j];
  }
#pragma unroll
  for (int m = 8; m <= 32; m <<= 1)
#pragma unroll
    for (int j = 0; j < 8; ++j) { s[j] += __shfl_xor(s[j], m); q[j] += __shfl_xor(q[j], m); }
  if ((t & 56) == 0) {
#pragma unroll
    for (int j = 0; j < 8; ++j) { pS[w][cg*8+j] = s[j]; pQ[w][cg*8+j] = q[j]; }
  }
  __syncthreads();
  if (t < 128) {
    int c = t & 63;
    if (t < 64) part[(size_t)blockIdx.x*128 + t] = pS[0][c]+pS[1][c]+pS[2][c]+pS[3][c];
    else        part[(size_t)blockIdx.x*128 + t] = pQ[0][c]+pQ[1][c]+pQ[2][c]+pQ[3][c];
  }
}

// ---- Layer 2: BN1+ReLU on stage, conv(64->128), max/min over K epilogue.
// h = t>>7 selects cout half; thread tile 8 rows x 8 couts (acc 64).
// Block = 128 rows = 4 points; wave covers (h, 2 points).
__global__ __launch_bounds__(256, 2) void layer2_kernel(
    const float* __restrict__ Y,
    const float* __restrict__ W, const float* __restrict__ bias,
    const float* __restrict__ sc, const float* __restrict__ sh,
    float* __restrict__ Ymax, float* __restrict__ Ymin,
    float* __restrict__ part)
{
  __shared__ __align__(16) float Xt[64][132];
  __shared__ __align__(16) float Wt[64][132];
  __shared__ float pS[4][64], pQ[4][64];
  const int t = threadIdx.x;
  for (int u = t; u < 64*128; u += 256) {
    int k = u >> 7, c = u & 127;
    Wt[k][c] = W[c*64 + k];
  }
  {
    const int row = t >> 1, half = t & 1;
    const int grow = blockIdx.x*128 + row;
    const float* yp = Y + (size_t)grow*64 + half*32;
#pragma unroll
    for (int u = 0; u < 8; ++u) {
      float4 v = *(const float4*)(yp + u*4);
      int c = half*32 + u*4;
      float4 scv = *(const float4*)(sc + c);
      float4 shv = *(const float4*)(sh + c);
      Xt[c+0][row] = fmaxf(0.f, scv.x*v.x + shv.x);
      Xt[c+1][row] = fmaxf(0.f, scv.y*v.y + shv.y);
      Xt[c+2][row] = fmaxf(0.f, scv.z*v.z + shv.z);
      Xt[c+3][row] = fmaxf(0.f, scv.w*v.w + shv.w);
    }
  }
  __syncthreads();
  const int h = t >> 7, s7 = t & 127;
  const int rg = s7 >> 3, cg = s7 & 7;     // rg 0..15 (8 rows each)
  const int r0 = rg*8;
  float acc[8][8];
  {
    float4 b0 = *(const float4*)(bias + h*64 + cg*8);
    float4 b1 = *(const float4*)(bias + h*64 + cg*8 + 4);
#pragma unroll
    for (int i = 0; i < 8; ++i) {
      acc[i][0]=b0.x; acc[i][1]=b0.y; acc[i][2]=b0.z; acc[i][3]=b0.w;
      acc[i][4]=b1.x; acc[i][5]=b1.y; acc[i][6]=b1.z; acc[i][7]=b1.w;
    }
  }
  for (int k = 0; k < 64; ++k) {
    float4 a0 = *(const float4*)&Xt[k][r0];
    float4 a1 = *(const float4*)&Xt[k][r0+4];
    float4 w0 = *(const float4*)&Wt[k][h*64 + cg*8];
    float4 w1 = *(const float4*)&Wt[k][h*64 + cg*8 + 4];
    float av[8] = {a0.x,a0.y,a0.z,a0.w,a1.x,a1.y,a1.z,a1.w};
    float bv[8] = {w0.x,w0.y,w0.z,w0.w,w1.x,w1.y,w1.z,w1.w};
#pragma unroll
    for (int i = 0; i < 8; ++i)
#pragma unroll
      for (int j = 0; j < 8; ++j) acc[i][j] += av[i]*bv[j];
  }
  const int w = t >> 6, lane = t & 63;
  // max/min over the 32 rows of each point (8 local + xor over rg bits 0,1)
  float mx[8], mn[8];
#pragma unroll
  for (int j = 0; j < 8; ++j) {
    float a = acc[0][j], bsm = acc[0][j];
#pragma unroll
    for (int i = 1; i < 8; ++i) { a = fmaxf(a, acc[i][j]); bsm = fminf(bsm, acc[i][j]); }
    mx[j] = a; mn[j] = bsm;
  }
#pragma unroll
  for (int m = 8; m <= 16; m <<= 1)
#pragma unroll
    for (int j = 0; j < 8; ++j) {
      mx[j] = fmaxf(mx[j], __shfl_xor(mx[j], m));
      mn[j] = fminf(mn[j], __shfl_xor(mn[j], m));
    }
  if ((lane & 24) == 0) {
    const int p = (w & 1)*2 + (lane >> 5);
    const size_t bs = (size_t)blockIdx.x*4 + p;
    float* dmx = Ymax + bs*128 + h*64 + cg*8;
    float* dmn = Ymin + bs*128 + h*64 + cg*8;
    *(float4*)(dmx)   = make_float4(mx[0],mx[1],mx[2],mx[3]);
    *(float4*)(dmx+4) = make_float4(mx[4],mx[5],mx[6],mx[7]);
    *(float4*)(dmn)   = make_float4(mn[0],mn[1],mn[2],mn[3]);
    *(float4*)(dmn+4) = make_float4(mn[4],mn[5],mn[6],mn[7]);
  }
  float s[8], q[8];
#pragma unroll
  for (int j = 0; j < 8; ++j) {
    float ts = 0.f, tq = 0.f;
#pragma unroll
    for (int i = 0; i < 8; ++i) { ts += acc[i][j]; tq += acc[i][j]*acc[i][j]; }
    s[j] = ts; q[j] = tq;
  }
#pragma unroll
  for (int m = 8; m <= 32; m <<= 1)
#pragma unroll
    for (int j = 0; j < 8; ++j) { s[j] += __shfl_xor(s[j], m); q[j] += __shfl_xor(q[j], m); }
  if ((lane & 56) == 0) {
#pragma unroll
    for (int j = 0; j < 8; ++j) { pS[w][cg*8+j] = s[j]; pQ[w][cg*8+j] = q[j]; }
  }
  __syncthreads();
  if (t < 128) {
    int c = t & 63, h2 = t >> 6;
    part[(size_t)blockIdx.x*256 + h2*64 + c]       = pS[2*h2][c] + pS[2*h2+1][c];
    part[(size_t)blockIdx.x*256 + 128 + h2*64 + c] = pQ[2*h2][c] + pQ[2*h2+1][c];
  }
}

// ============ deterministic tree reduce of block partials ============
__global__ __launch_bounds__(256) void reduce_kernel(const float* __restrict__ part,
                                                     int nb, int stride,
                                                     float* __restrict__ sums)
{
  const int j = blockIdx.x;
  const int t = threadIdx.x;
  float s = 0.f;
  for (int i = t; i < nb; i += 256) s += part[(size_t)i*stride + j];
  __shared__ float buf[256];
  buf[t] = s;
  __syncthreads();
  for (int m = 128; m > 0; m >>= 1) {
    if (t < m) buf[t] += buf[t + m];
    __syncthreads();
  }
  if (t == 0) sums[j] = buf[0];
}

__global__ void finalize_kernel(const float* __restrict__ sums, int cout,
                                const float* __restrict__ g, const float* __restrict__ be,
                                float* __restrict__ scsh)
{
  int o = threadIdx.x;
  if (o < cout) {
    const float n = (float)NROWS;
    float mean = sums[o] / n;
    float var  = sums[cout + o] / n - mean*mean;
    float sc   = g[o] / sqrtf(var + 1e-5f);
    scsh[o]        = sc;
    scsh[cout + o] = be[o] - mean*sc;
  }
}

__global__ __launch_bounds__(256) void out_kernel(const float* __restrict__ Ymax,
                                                  const float* __restrict__ Ymin,
                                                  const float* __restrict__ scsh,
                                                  float* __restrict__ outx)
{
  const int e = blockIdx.x*256 + threadIdx.x;
  const int o = e & 127;
  float sc = scsh[o], sh = scsh[128 + o];
  float v = (sc >= 0.f) ? Ymax[e] : Ymin[e];
  outx[e] = fmaxf(0.f, sc*v + sh);
}

// ============================ launcher ============================
extern "C" void kernel_launch(void* const* d_in, const int* in_sizes, int n_in,
                              void* d_out, int out_size, void* d_ws, size_t ws_size,
                              hipStream_t stream)
{
  (void)in_sizes; (void)n_in; (void)out_size; (void)ws_size;
  const float* xyz  = (const float*)d_in[0];
  const float* feat = (const float*)d_in[1];
  const float* W0 = (const float*)d_in[2];
  const float* b0 = (const float*)d_in[3];
  const float* g0 = (const float*)d_in[4];
  const float* e0 = (const float*)d_in[5];
  const float* W1 = (const float*)d_in[6];
  const float* b1 = (const float*)d_in[7];
  const float* g1 = (const float*)d_in[8];
  const float* e1 = (const float*)d_in[9];
  const float* W2 = (const float*)d_in[10];
  const float* b2 = (const float*)d_in[11];
  const float* g2 = (const float*)d_in[12];
  const float* e2 = (const float*)d_in[13];

  float* out_newxyz = (float*)d_out;
  float* out_x      = (float*)d_out + BB*SS*3;

  constexpr size_t OFF_IDX  = 0;                         // 2 MB
  constexpr size_t OFF_Y    = 2097152;                   // 134 MB
  constexpr size_t OFF_YMAX = OFF_Y    + 134217728;      // 8 MB
  constexpr size_t OFF_YMIN = OFF_YMAX + 8388608;        // 8 MB
  constexpr size_t OFF_PART = OFF_YMIN + 8388608;        // 4 MB
  constexpr size_t OFF_SUMS = OFF_PART + 4194304;
  constexpr size_t OFF_SCSH = OFF_SUMS + 3072;

  char* ws = (char*)d_ws;
  int*   idxb  = (int*)  (ws + OFF_IDX);
  float* Y     = (float*)(ws + OFF_Y);
  float* Ymax  = (float*)(ws + OFF_YMAX);
  float* Ymin  = (float*)(ws + OFF_YMIN);
  float* part  = (float*)(ws + OFF_PART);
  float* sums0 = (float*)(ws + OFF_SUMS);
  float* sums1 = sums0 + 256;
  float* sums2 = sums1 + 256;
  float* scsh0 = (float*)(ws + OFF_SCSH);
  float* scsh1 = scsh0 + 256;
  float* scsh2 = scsh1 + 256;

  fps_kernel  <<<BB, 256, 0, stream>>>(xyz, out_newxyz);
  ballq_kernel<<<256, 256, 0, stream>>>(xyz, out_newxyz, idxb);

  layer0_kernel<<<NROWS/128, 256, 0, stream>>>(xyz, feat, out_newxyz, idxb, W0, b0, Y, part);
  reduce_kernel<<<128, 256, 0, stream>>>(part, NROWS/128, 128, sums0);
  finalize_kernel<<<1, 128, 0, stream>>>(sums0, 64, g0, e0, scsh0);

  layer1_kernel<<<NROWS/128, 256, 0, stream>>>(Y, W1, b1, scsh0, scsh0 + 64, part);
  reduce_kernel<<<128, 256, 0, stream>>>(part, NROWS/128, 128, sums1);
  finalize_kernel<<<1, 128, 0, stream>>>(sums1, 64, g1, e1, scsh1);

  layer2_kernel<<<NROWS/128, 256, 0, stream>>>(Y, W2, b2, scsh1, scsh1 + 64, Ymax, Ymin, part);
  reduce_kernel<<<256, 256, 0, stream>>>(part, NROWS/128, 256, sums2);
  finalize_kernel<<<1, 128, 0, stream>>>(sums2, 128, g2, e2, scsh2);

  out_kernel<<<BB*SS*128/256, 256, 0, stream>>>(Ymax, Ymin, scsh2, out_x);
}